// Round 10
// baseline (451.123 us; speedup 1.0000x reference)
//
#include <hip/hip_runtime.h>
#include <hip/hip_fp16.h>

#define CCH 128      // FEATURE_DIM (channels)
#define NCP 25
#define HH  128      // plane H
#define WW  128      // plane W
#define NPIX (HH * WW)
#define NCHUNK 4

// ------------- Transpose+convert (B,C,H,W) f32 -> (B,H,W,C) f16 -------------
__global__ __launch_bounds__(256) void transpose_f16_kernel(
    const float* __restrict__ s0, const float* __restrict__ s1, const float* __restrict__ s2,
    __half* __restrict__ d0, __half* __restrict__ d1, __half* __restrict__ d2)
{
    __shared__ float tile[64][65];
    const int z = blockIdx.z;           // b*3 + plane
    const int b = z / 3, pl = z - 3 * b;
    const float* src = (pl == 0 ? s0 : pl == 1 ? s1 : s2) + (size_t)b * CCH * NPIX;
    __half* dst      = (pl == 0 ? d0 : pl == 1 ? d1 : d2) + (size_t)b * CCH * NPIX;
    const int n0 = blockIdx.x * 64;
    const int c0 = blockIdx.y * 64;
    const int tx = threadIdx.x;         // 0..63
    const int ty = threadIdx.y;         // 0..3

    #pragma unroll
    for (int cc = 0; cc < 64; cc += 4)
        tile[cc + ty][tx] = src[(size_t)(c0 + cc + ty) * NPIX + (n0 + tx)];
    __syncthreads();
    #pragma unroll
    for (int nn = 0; nn < 64; nn += 4)
        dst[(size_t)(n0 + nn + ty) * CCH + (c0 + tx)] = __float2half(tile[tx][nn + ty]);
}

// ------------- sample helpers (channel-pair per lane) -----------------------
struct Ctx2 { int off; __half2 wxh, wyh; };  // off in __half2 units

__device__ __forceinline__ Ctx2 mkctx2(int lane, float u, float v) {
    float x = fminf(fmaxf(u, 0.f), 1.f) * 127.f;
    float y = fminf(fmaxf(v, 0.f), 1.f) * 127.f;
    int x0 = (int)floorf(x); x0 = x0 > 126 ? 126 : x0;
    int y0 = (int)floorf(y); y0 = y0 > 126 ? 126 : y0;
    Ctx2 c;
    c.wxh = __float2half2_rn(x - (float)x0);
    c.wyh = __float2half2_rn(y - (float)y0);
    c.off = (y0 * WW + x0) * 64 + lane;   // 64 half2 per pixel (128 ch)
    return c;
}

__device__ __forceinline__ __half2 samp2(const __half2* __restrict__ P, Ctx2 c) {
    __half2 f00 = P[c.off];
    __half2 f01 = P[c.off + 64];
    __half2 f10 = P[c.off + 8192];
    __half2 f11 = P[c.off + 8256];
    __half2 top = __hfma2(__hsub2(f01, f00), c.wxh, f00);
    __half2 bot = __hfma2(__hsub2(f11, f10), c.wxh, f10);
    return __hfma2(__hsub2(bot, top), c.wyh, top);
}

// ------------- Main fused kernel: chunked grid-stride -----------------------
// Per chunk: block handles 2 queries. Waves 0,1 -> query 0; waves 2,3 -> query 1.
// Within a query: wave half 0 = feature + anchors 0..11; half 1 = anchors 12..24.
// lane owns channels (2*lane, 2*lane+1).
__global__ __launch_bounds__(256, 8) void equi_chunk_kernel(
    const float* __restrict__ qp,    // (bs, ns, 9)
    const __half* __restrict__ cxz,  // (bs, NPIX, C) f16
    const __half* __restrict__ cxy,
    const __half* __restrict__ cyz,
    const float* __restrict__ cp,    // (NCP, 3)
    const float* __restrict__ Wv,    // (C, HID)
    const float* __restrict__ bv,
    const float* __restrict__ Ww,    // (C, NCP)
    const float* __restrict__ bw,
    const float* __restrict__ Wo,    // (HID, C)
    const float* __restrict__ bo,
    float* __restrict__ out,         // (bs, ns, C)
    int ns, int qPerChunk)
{
    // bijective XCD swizzle within each chunk
    const int nwg = gridDim.x;
    const int bid = blockIdx.x;
    const int qq = nwg >> 3, rr = nwg & 7;
    const int xcd = bid & 7, loc = bid >> 3;
    const int swz = (xcd < rr ? xcd * (qq + 1) : rr * (qq + 1) + (xcd - rr) * qq) + loc;

    const int t    = threadIdx.x;
    const int w    = t >> 6;             // wave 0..3
    const int qsel = w >> 1;             // 0,1 : which of the 2 queries
    const int half = w & 1;              // 0: feature + g<12, 1: g>=12
    const int lane = t & 63;

    const size_t planeStride = (size_t)CCH * NPIX;

    __shared__ __align__(16) float sFeat[2][CCH];
    __shared__ __align__(16) float sA[2][CCH];
    __shared__ __align__(16) float sB[2][CCH];
    __shared__ __align__(16) float sPre[2][CCH];
    __shared__ float sW[2][28];
    __shared__ float sSw[2];

    // descending chunk order: last-transposed batches (L3-warm) first
    for (int cc = NCHUNK - 1; cc >= 0; --cc) {
        const int qbase = cc * qPerChunk;
        const int qglob = qbase + swz * 2 + qsel;    // this wave's query
        const int b = qglob / ns;

        const __half2* P0 = (const __half2*)(cxz + (size_t)b * planeStride);
        const __half2* P1 = (const __half2*)(cxy + (size_t)b * planeStride);
        const __half2* P2 = (const __half2*)(cyz + (size_t)b * planeStride);

        const float* qptr = qp + (size_t)qglob * 9;
        const float px = qptr[0], py = qptr[1], pz = qptr[2];
        const float a1x = qptr[3], a1y = qptr[4], a1z = qptr[5];
        const float a2x = qptr[6], a2y = qptr[7], a2z = qptr[8];

        // rot6d -> matrix (rows b1,b2,b3)
        float n1 = rsqrtf(a1x * a1x + a1y * a1y + a1z * a1z);
        float b1x = a1x * n1, b1y = a1y * n1, b1z = a1z * n1;
        float dd = b1x * a2x + b1y * a2y + b1z * a2z;
        float u2x = a2x - dd * b1x, u2y = a2y - dd * b1y, u2z = a2z - dd * b1z;
        float n2 = rsqrtf(u2x * u2x + u2y * u2y + u2z * u2z);
        float b2x = u2x * n2, b2y = u2y * n2, b2z = u2z * n2;
        float b3x = b1y * b2z - b1z * b2y;
        float b3y = b1z * b2x - b1x * b2z;
        float b3z = b1x * b2y - b1y * b2x;

        // ---- phase 1: feature sample (half-0 waves) ----
        if (half == 0) {
            Ctx2 c0 = mkctx2(lane, px, pz);
            Ctx2 c1 = mkctx2(lane, px, py);
            Ctx2 c2 = mkctx2(lane, py, pz);
            __half2 s = __hadd2(__hadd2(samp2(P0, c0), samp2(P1, c1)), samp2(P2, c2));
            float2 f = __half22float2(s);
            sFeat[qsel][lane * 2]     = f.x;
            sFeat[qsel][lane * 2 + 1] = f.y;
        }
        __syncthreads();

        // ---- phase 2: weights[q][g] = feat[q].Ww[:,g] + bw[g] (50 outputs) ----
        if (t < 2 * NCP) {
            int qi = t / NCP, g = t - qi * NCP;
            float acc = bw[g];
            #pragma unroll 8
            for (int c = 0; c < CCH; ++c)
                acc += sFeat[qi][c] * Ww[c * NCP + g];
            sW[qi][g] = acc;
        }
        __syncthreads();
        if (t < 2) {
            float s = 0.f;
            #pragma unroll
            for (int g = 0; g < NCP; ++g) s += sW[t][g];
            sSw[t] = s;   // consumed after next barrier
        }

        // ---- phase 3: anchor gather; halves split anchors 12/13 ----
        float ac0 = 0.f, ac1 = 0.f;
        const int gbeg = half ? 12 : 0;
        const int gend = half ? 25 : 12;
        for (int g = gbeg; g < gend; ++g) {
            float cpx = cp[g * 3 + 0], cpy = cp[g * 3 + 1], cpz = cp[g * 3 + 2];
            float ax = px + b1x * cpx + b1y * cpy + b1z * cpz;
            float ay = py + b2x * cpx + b2y * cpy + b2z * cpz;
            float az = pz + b3x * cpx + b3y * cpy + b3z * cpz;
            Ctx2 c0 = mkctx2(lane, ax, az);
            Ctx2 c1 = mkctx2(lane, ax, ay);
            Ctx2 c2 = mkctx2(lane, ay, az);
            __half2 s = __hadd2(__hadd2(samp2(P0, c0), samp2(P1, c1)), samp2(P2, c2));
            float2 f = __half22float2(s);
            float wg = sW[qsel][g];
            ac0 += wg * f.x;
            ac1 += wg * f.y;
        }
        {
            float* dst = half ? &sB[qsel][lane * 2] : &sA[qsel][lane * 2];
            dst[0] = ac0;
            dst[1] = ac1;
        }
        __syncthreads();

        // ---- phase 4: pre[q][h] = sSw[q]*bv[h] + sum_c (A+B)[q][c]*Wv[c][h] ----
        if (t < CCH) {
            const int h = t;
            float bvh = bv[h];
            float p0 = sSw[0] * bvh;
            float p1 = sSw[1] * bvh;
            #pragma unroll 4
            for (int c = 0; c < CCH; ++c) {
                float wv = Wv[c * CCH + h];
                p0 += (sA[0][c] + sB[0][c]) * wv;
                p1 += (sA[1][c] + sB[1][c]) * wv;
            }
            sPre[0][h] = p0;
            sPre[1][h] = p1;
        }
        __syncthreads();

        // ---- phase 5: out[q][c] = bo[c] + feat[q][c] + sum_h pre[q][h]*Wo[h][c] ----
        if (t < CCH) {
            const int ci = t;
            float boc = bo[ci];
            float o0 = boc + sFeat[0][ci];
            float o1 = boc + sFeat[1][ci];
            #pragma unroll 4
            for (int h = 0; h < CCH; ++h) {
                float wo = Wo[h * CCH + ci];
                o0 += sPre[0][h] * wo;
                o1 += sPre[1][h] * wo;
            }
            const int qout = qbase + swz * 2;
            out[(size_t)qout * CCH + ci]       = o0;
            out[(size_t)(qout + 1) * CCH + ci] = o1;
        }
        __syncthreads();   // protect shared buffers before next chunk
    }
}

// ------------- Fallback (channel-first fp32, no workspace) ------------------
__device__ __forceinline__ float bilin_cf(const float* __restrict__ pl, int c, float u, float v) {
    float x = fminf(fmaxf(u, 0.f), 1.f) * (float)(WW - 1);
    float y = fminf(fmaxf(v, 0.f), 1.f) * (float)(HH - 1);
    int x0 = (int)floorf(x); x0 = x0 > (WW - 2) ? (WW - 2) : x0;
    int y0 = (int)floorf(y); y0 = y0 > (HH - 2) ? (HH - 2) : y0;
    float wx = x - (float)x0;
    float wy = y - (float)y0;
    const float* p = pl + ((size_t)c << 14) + (y0 << 7) + x0;
    float top = p[0] * (1.f - wx) + p[1] * wx;
    float bot = p[WW] * (1.f - wx) + p[WW + 1] * wx;
    return top * (1.f - wy) + bot * wy;
}

__global__ __launch_bounds__(128) void equi_attn_cf_kernel(
    const float* __restrict__ qp, const float* __restrict__ cxz,
    const float* __restrict__ cxy, const float* __restrict__ cyz,
    const float* __restrict__ cp, const float* __restrict__ Wv,
    const float* __restrict__ bv, const float* __restrict__ Ww,
    const float* __restrict__ bw, const float* __restrict__ Wo,
    const float* __restrict__ bo, float* __restrict__ out, int ns)
{
    const int q = blockIdx.x, b = q / ns, tid = threadIdx.x;
    const size_t planeStride = (size_t)CCH * NPIX;
    const float* pxz = cxz + (size_t)b * planeStride;
    const float* pxy = cxy + (size_t)b * planeStride;
    const float* pyz = cyz + (size_t)b * planeStride;
    const float* qptr = qp + (size_t)q * 9;
    const float px = qptr[0], py = qptr[1], pz = qptr[2];
    const float a1x = qptr[3], a1y = qptr[4], a1z = qptr[5];
    const float a2x = qptr[6], a2y = qptr[7], a2z = qptr[8];
    float n1 = rsqrtf(a1x * a1x + a1y * a1y + a1z * a1z);
    float b1x = a1x * n1, b1y = a1y * n1, b1z = a1z * n1;
    float dd = b1x * a2x + b1y * a2y + b1z * a2z;
    float u2x = a2x - dd * b1x, u2y = a2y - dd * b1y, u2z = a2z - dd * b1z;
    float n2 = rsqrtf(u2x * u2x + u2y * u2y + u2z * u2z);
    float b2x = u2x * n2, b2y = u2y * n2, b2z = u2z * n2;
    float b3x = b1y * b2z - b1z * b2y;
    float b3y = b1z * b2x - b1x * b2z;
    float b3z = b1x * b2y - b1y * b2x;
    __shared__ float sFeat[CCH]; __shared__ float sW[32];
    __shared__ float sWsum[CCH]; __shared__ float sPre[CCH];
    float feat = bilin_cf(pxz, tid, px, pz) + bilin_cf(pxy, tid, px, py) + bilin_cf(pyz, tid, py, pz);
    sFeat[tid] = feat;
    __syncthreads();
    if (tid < NCP) {
        float acc = bw[tid];
        for (int c = 0; c < CCH; ++c) acc += sFeat[c] * Ww[c * NCP + tid];
        sW[tid] = acc;
    }
    __syncthreads();
    float sw = 0.f;
    #pragma unroll
    for (int g = 0; g < NCP; ++g) sw += sW[g];
    float wacc = 0.f;
    for (int g = 0; g < NCP; ++g) {
        float cx = cp[g * 3 + 0], cy = cp[g * 3 + 1], cz = cp[g * 3 + 2];
        float ax = px + b1x * cx + b1y * cy + b1z * cz;
        float ay = py + b2x * cx + b2y * cy + b2z * cz;
        float az = pz + b3x * cx + b3y * cy + b3z * cz;
        wacc += sW[g] * (bilin_cf(pxz, tid, ax, az) + bilin_cf(pxy, tid, ax, ay) + bilin_cf(pyz, tid, ay, az));
    }
    sWsum[tid] = wacc;
    __syncthreads();
    float pre = sw * bv[tid];
    for (int c = 0; c < CCH; ++c) pre += sWsum[c] * Wv[c * CCH + tid];
    sPre[tid] = pre;
    __syncthreads();
    float o = bo[tid] + feat;
    for (int h = 0; h < CCH; ++h) o += sPre[h] * Wo[h * CCH + tid];
    out[(size_t)q * CCH + tid] = o;
}

extern "C" void kernel_launch(void* const* d_in, const int* in_sizes, int n_in,
                              void* d_out, int out_size, void* d_ws, size_t ws_size,
                              hipStream_t stream) {
    const float* qp  = (const float*)d_in[0];
    const float* cxz = (const float*)d_in[1];
    const float* cxy = (const float*)d_in[2];
    const float* cyz = (const float*)d_in[3];
    const float* cp  = (const float*)d_in[4];
    const float* Wv  = (const float*)d_in[5];
    const float* bv  = (const float*)d_in[6];
    const float* Ww  = (const float*)d_in[7];
    const float* bw  = (const float*)d_in[8];
    const float* Wo  = (const float*)d_in[9];
    const float* bo  = (const float*)d_in[10];
    float* out = (float*)d_out;

    const int bs = in_sizes[1] / (CCH * NPIX);
    const int ns = in_sizes[0] / (bs * 9);
    const int nq = bs * ns;

    const size_t planeFloats = (size_t)bs * CCH * NPIX;     // per plane
    const size_t needBytes = 3 * planeFloats * sizeof(__half);

    // need: nq divisible by 2*NCHUNK (2 queries/block/chunk)
    if (ws_size >= needBytes && (nq % (2 * NCHUNK)) == 0) {
        __half* t_xz = (__half*)d_ws;
        __half* t_xy = t_xz + planeFloats;
        __half* t_yz = t_xy + planeFloats;

        dim3 tgrid(NPIX / 64, CCH / 64, bs * 3);
        dim3 tblk(64, 4);
        transpose_f16_kernel<<<tgrid, tblk, 0, stream>>>(cxz, cxy, cyz, t_xz, t_xy, t_yz);

        const int qPerChunk = nq / NCHUNK;
        const int nblk = qPerChunk / 2;
        equi_chunk_kernel<<<nblk, 256, 0, stream>>>(
            qp, t_xz, t_xy, t_yz, cp, Wv, bv, Ww, bw, Wo, bo, out, ns, qPerChunk);
    } else {
        equi_attn_cf_kernel<<<nq, 128, 0, stream>>>(
            qp, cxz, cxy, cyz, cp, Wv, bv, Ww, bw, Wo, bo, out, ns);
    }
}